// Round 1
// baseline (123.937 us; speedup 1.0000x reference)
//
#include <hip/hip_runtime.h>
#include <hip/hip_bf16.h>

#define B_N  4096
#define K_D  1024
#define TILE 128
#define BK   64

typedef __bf16 bf16x8 __attribute__((ext_vector_type(8)));
typedef float  f32x4  __attribute__((ext_vector_type(4)));

// round-to-nearest-even float -> bf16 bits (inputs are finite normals; no NaN path needed)
__device__ __forceinline__ unsigned short f2bf(float x) {
    union { float f; unsigned int u; } v; v.f = x;
    unsigned int r = v.u + 0x7fffu + ((v.u >> 16) & 1u);
    return (unsigned short)(r >> 16);
}

// One block (256 threads) per row: compute L2 norm, write bf16 normalized row.
__global__ void normalize_bf16(const float* __restrict__ f, unsigned short* __restrict__ fnb) {
    const int row = blockIdx.x;
    const int tid = threadIdx.x;
    float4 v = ((const float4*)(f + (size_t)row * K_D))[tid];
    float s = v.x * v.x + v.y * v.y + v.z * v.z + v.w * v.w;
#pragma unroll
    for (int m = 1; m < 64; m <<= 1) s += __shfl_xor(s, m, 64);
    __shared__ float wsum[4];
    if ((tid & 63) == 0) wsum[tid >> 6] = s;
    __syncthreads();
    float tot = wsum[0] + wsum[1] + wsum[2] + wsum[3];
    float scale = 1.0f / fmaxf(sqrtf(tot), 1e-12f);
    ushort4 o;
    o.x = f2bf(v.x * scale); o.y = f2bf(v.y * scale);
    o.z = f2bf(v.z * scale); o.w = f2bf(v.w * scale);
    ((ushort4*)(fnb + (size_t)row * K_D))[tid] = o;
}

// 128x128 tile of sim = fn*fn^T (both operands row-major, i.e. a BT-gemm).
// 4 waves in 2x2; each wave owns a 64x64 quadrant = 4x4 fragments of 16x16x32 bf16 MFMA.
// Epilogue: e = exp(10*dot) (0 on diagonal); rowsum via 16-lane butterflies + atomics;
// possum (same-label pairs) via wave+block reduction + 1 atomic per block.
__global__ void gemm_exp_reduce(const unsigned short* __restrict__ fnb,
                                const int* __restrict__ labels,
                                float* __restrict__ rowsum,
                                float* __restrict__ possum) {
    __shared__ __align__(16) unsigned short As[TILE * BK]; // 16 KB
    __shared__ __align__(16) unsigned short Bs[TILE * BK]; // 16 KB
    __shared__ int   rlab[TILE];
    __shared__ int   clab[TILE];
    __shared__ float posred[4];

    const int bi = blockIdx.y, bj = blockIdx.x;
    const int row0 = bi * TILE, col0 = bj * TILE;
    const int tid  = threadIdx.x;
    const int lane = tid & 63, wave = tid >> 6;
    const int wr = wave >> 1, wc = wave & 1;
    const int quad = lane >> 4, l15 = lane & 15;

    if (tid < TILE) rlab[tid] = labels[row0 + tid];
    else            clab[tid - TILE] = labels[col0 + tid - TILE];

    f32x4 acc[4][4];
#pragma unroll
    for (int i = 0; i < 4; ++i)
#pragma unroll
        for (int j = 0; j < 4; ++j) {
            f32x4 z = {0.f, 0.f, 0.f, 0.f};
            acc[i][j] = z;
        }

    for (int k0 = 0; k0 < K_D; k0 += BK) {
        // Stage A (rows row0..row0+127, k0..k0+63) and B (rows col0..) as [128][64] bf16.
        // Flat chunk c = it*256+tid covers elements [c*8, c*8+8): LDS dst = base + lane*16
        // in exact lane order (contiguous), as global_load_lds requires.
#pragma unroll
        for (int it = 0; it < 4; ++it) {
            int c  = it * 256 + tid;
            int r  = c >> 3;
            int cc = (c & 7) << 3;
            __builtin_amdgcn_global_load_lds(
                (const unsigned int*)(fnb + (size_t)(row0 + r) * K_D + k0 + cc),
                (unsigned int*)&As[c * 8], 16, 0, 0);
            __builtin_amdgcn_global_load_lds(
                (const unsigned int*)(fnb + (size_t)(col0 + r) * K_D + k0 + cc),
                (unsigned int*)&Bs[c * 8], 16, 0, 0);
        }
        __syncthreads();

#pragma unroll
        for (int kk = 0; kk < BK; kk += 32) {
            bf16x8 af[4], bf[4];
#pragma unroll
            for (int fr = 0; fr < 4; ++fr)
                af[fr] = *(const bf16x8*)&As[(wr * 64 + fr * 16 + l15) * BK + kk + quad * 8];
#pragma unroll
            for (int fc = 0; fc < 4; ++fc)
                bf[fc] = *(const bf16x8*)&Bs[(wc * 64 + fc * 16 + l15) * BK + kk + quad * 8];
#pragma unroll
            for (int fr = 0; fr < 4; ++fr)
#pragma unroll
                for (int fc = 0; fc < 4; ++fc)
                    acc[fr][fc] = __builtin_amdgcn_mfma_f32_16x16x32_bf16(
                        af[fr], bf[fc], acc[fr][fc], 0, 0, 0);
        }
        __syncthreads();
    }

    // Epilogue. C/D layout (m89/m91-verified): col = lane&15, row = quad*4 + reg.
    float pospart = 0.0f;
#pragma unroll
    for (int fr = 0; fr < 4; ++fr) {
        float rp[4] = {0.f, 0.f, 0.f, 0.f};
#pragma unroll
        for (int fc = 0; fc < 4; ++fc) {
            int c    = wc * 64 + fc * 16 + l15;
            int gcol = col0 + c;
            int cl   = clab[c];
#pragma unroll
            for (int r = 0; r < 4; ++r) {
                int rr   = wr * 64 + fr * 16 + quad * 4 + r;
                int grow = row0 + rr;
                float e  = (grow == gcol) ? 0.0f : __expf(acc[fr][fc][r] * 10.0f);
                rp[r] += e;
                pospart += (rlab[rr] == cl) ? e : 0.0f;
            }
        }
        // sum across the 16 columns (lanes sharing a quad)
#pragma unroll
        for (int r = 0; r < 4; ++r) {
            float v = rp[r];
            v += __shfl_xor(v, 1, 64);
            v += __shfl_xor(v, 2, 64);
            v += __shfl_xor(v, 4, 64);
            v += __shfl_xor(v, 8, 64);
            if (l15 == 0)
                atomicAdd(&rowsum[row0 + wr * 64 + fr * 16 + quad * 4 + r], v);
        }
    }
#pragma unroll
    for (int m = 1; m < 64; m <<= 1) pospart += __shfl_xor(pospart, m, 64);
    if (lane == 0) posred[wave] = pospart;
    __syncthreads();
    if (tid == 0)
        atomicAdd(possum, posred[0] + posred[1] + posred[2] + posred[3]);
}

__global__ void finalize(const float* __restrict__ rowsum,
                         const float* __restrict__ possum,
                         float* __restrict__ out) {
    const int tid = threadIdx.x;
    float s = 0.f;
    for (int i = tid; i < B_N; i += 256) s += logf(rowsum[i]);
#pragma unroll
    for (int m = 1; m < 64; m <<= 1) s += __shfl_xor(s, m, 64);
    __shared__ float w[4];
    if ((tid & 63) == 0) w[tid >> 6] = s;
    __syncthreads();
    if (tid == 0) {
        float tot = w[0] + w[1] + w[2] + w[3];
        // loss = mean_i log(rowsum_i)  -  log(possum)
        out[0] = tot / (float)B_N - logf(possum[0]);
    }
}

extern "C" void kernel_launch(void* const* d_in, const int* in_sizes, int n_in,
                              void* d_out, int out_size, void* d_ws, size_t ws_size,
                              hipStream_t stream) {
    const float* features = (const float*)d_in[0];
    const int*   targets  = (const int*)d_in[1];
    float*       out      = (float*)d_out;

    // workspace layout: [bf16 fn: 8 MB][rowsum: 4096 f32][possum: 1 f32]
    unsigned short* fnb    = (unsigned short*)d_ws;
    float*          rowsum = (float*)((char*)d_ws + (size_t)B_N * K_D * sizeof(unsigned short));
    float*          possum = rowsum + B_N;

    hipMemsetAsync(rowsum, 0, (B_N + 1) * sizeof(float), stream);
    normalize_bf16<<<B_N, 256, 0, stream>>>(features, fnb);
    dim3 grid(B_N / TILE, B_N / TILE);
    gemm_exp_reduce<<<grid, 256, 0, stream>>>(fnb, targets, rowsum, possum);
    finalize<<<1, 256, 0, stream>>>(rowsum, possum, out);
}